// Round 3
// baseline (160.780 us; speedup 1.0000x reference)
//
#include <hip/hip_runtime.h>
#include <hip/hip_bf16.h>

// LSTM_71382356459716 R2: weight-stationary MFMA, trans-pipe-lean version.
// 1024 blocks x 4 waves; each wave owns 16 hidden units (4 M-tiles of the
// unit-major-permuted 256x96 gate matrix, stationary in 48 VGPRs); block owns
// 16 batch rows. x B-frags load straight from global (no LDS staging), bias
// enters as MFMA C operand, bf16 converts use packed v_cvt_pk_bf16_f32.
// LDS holds only the double-buffered h tile (2x16x72 bf16 = 4.6 KB), row
// stride 144B = 9*16B (odd multiple -> conflict-free ds_read_b128).

namespace {
constexpr int B_TOT   = 16384;
constexpr int T_STEPS = 28;
constexpr int IN_DIM  = 28;
constexpr int HID     = 64;
constexpr int OUT_DIM = 10;
constexpr int ROWS    = 16;    // batch rows per block -> 1024 blocks, 4/CU
constexpr int THREADS = 256;   // 4 waves
constexpr int KP      = 72;    // h row stride in shorts (144 B)
constexpr int XROW    = T_STEPS * IN_DIM;  // 784 floats per batch row
}

typedef __attribute__((ext_vector_type(8))) short short8v;   // 8 bf16
typedef __attribute__((ext_vector_type(4))) float float4v;
typedef __attribute__((ext_vector_type(4))) int   int4v;

__device__ __forceinline__ short f2bf_cold(float f) {   // init path only
  union { float f; unsigned u; } v; v.f = f;
  unsigned r = v.u + 0x7FFFu + ((v.u >> 16) & 1u);
  return (short)(r >> 16);
}
__device__ __forceinline__ float bf2f(short s) {
  union { unsigned u; float f; } v; v.u = ((unsigned)(unsigned short)s) << 16;
  return v.f;
}
__device__ __forceinline__ unsigned pk2(float a, float b) {  // 2xf32 -> packed bf16x2
  __hip_bfloat162 h = __float22bfloat162_rn(float2{a, b});
  union { __hip_bfloat162 h; unsigned u; } cv; cv.h = h; return cv.u;
}
__device__ __forceinline__ float sigf(float v) {
  return __builtin_amdgcn_rcpf(1.0f + __expf(-v));
}
__device__ __forceinline__ float tanh_f(float v) {
  return 2.0f * __builtin_amdgcn_rcpf(1.0f + __expf(-2.0f * v)) - 1.0f;
}

__global__ __launch_bounds__(THREADS, 4)
void lstm_mfma2(const float* __restrict__ x, const float* __restrict__ W_ih,
                const float* __restrict__ W_hh, const float* __restrict__ b_ih,
                const float* __restrict__ b_hh, const float* __restrict__ W_fc,
                const float* __restrict__ b_fc, float* __restrict__ out) {
  __shared__ short hs[2][ROWS][KP];   // [buf][row][unit], bf16

  const int tid  = threadIdx.x;
  const int lane = tid & 63;
  const int w    = tid >> 6;      // wave 0..3 -> units 16w..16w+15
  const int l15  = lane & 15;
  const int q    = lane >> 4;     // 0..3
  const int b0   = blockIdx.x * ROWS;

  // ---- stationary A (weights), gate rows permuted unit-major m = unit*4+type
  // A-frag: lane holds A[m = 16*mt + l15][k = kc*32 + q*8 + j].
  // k: 0..27 = W_ih cols, 28..31 = 0, 32..95 = W_hh cols.
  short8v a[4][3];
  float4v bias[4];
#pragma unroll
  for (int i = 0; i < 4; ++i) {
    const int mt   = 4 * w + i;
    const int m    = 16 * mt + l15;
    const int unit = m >> 2, type = m & 3;
    const int g    = type * 64 + unit;
#pragma unroll
    for (int kc = 0; kc < 3; ++kc) {
      short8v frag;
#pragma unroll
      for (int j = 0; j < 8; ++j) {
        const int k = kc * 32 + q * 8 + j;
        float v = 0.0f;
        if (k < IN_DIM)   v = W_ih[g * IN_DIM + k];
        else if (k >= 32) v = W_hh[g * HID + (k - 32)];
        frag[j] = f2bf_cold(v);
      }
      a[i][kc] = frag;
    }
    const int ub = 4 * mt + q;    // the unit this lane's C regs belong to
    float4v bv;
#pragma unroll
    for (int r = 0; r < 4; ++r) bv[r] = b_ih[r * 64 + ub] + b_hh[r * 64 + ub];
    bias[i] = bv;
  }

  // zero h buffers
  for (int idx = tid; idx < 2 * ROWS * KP; idx += THREADS) (&hs[0][0][0])[idx] = 0;
  __syncthreads();

  // ---- x direct-from-global: lane (l15,q) covers row b0+l15, k = q*8..q*8+7
  const float* xrow = x + (size_t)(b0 + l15) * XROW + q * 8;
  float4 lo = *(const float4*)xrow;                       // t = 0
  float4 hi = {0.f, 0.f, 0.f, 0.f};
  if (q < 3) hi = *(const float4*)(xrow + 4);             // q==3: k 28..31 are pad

  float c_state[4] = {0.f, 0.f, 0.f, 0.f};

  for (int t = 0; t < T_STEPS; ++t) {
    const int cur = t & 1, nxt = cur ^ 1;

    // pack this step's x frag (consumes lo/hi loaded last iteration)
    int4v xi;
    xi[0] = pk2(lo.x, lo.y); xi[1] = pk2(lo.z, lo.w);
    xi[2] = pk2(hi.x, hi.y); xi[3] = pk2(hi.z, hi.w);
    union { int4v i; short8v s; } xb; xb.i = xi;

    // h B-frags from LDS: lane holds B[k = 32 + kc*32 + q*8 + j][n = l15]
    short8v hf0 = *(const short8v*)&hs[cur][l15][q * 8];
    short8v hf1 = *(const short8v*)&hs[cur][l15][32 + q * 8];

    // prefetch next step's x (latency hides under MFMA + activations)
    if (t + 1 < T_STEPS) {
      const float* xp = xrow + (t + 1) * IN_DIM;
      lo = *(const float4*)xp;
      if (q < 3) hi = *(const float4*)(xp + 4);
    }

    float4v acc[4];
#pragma unroll
    for (int i = 0; i < 4; ++i)
      acc[i] = __builtin_amdgcn_mfma_f32_16x16x32_bf16(a[i][0], xb.s, bias[i], 0, 0, 0);
#pragma unroll
    for (int i = 0; i < 4; ++i)
      acc[i] = __builtin_amdgcn_mfma_f32_16x16x32_bf16(a[i][1], hf0, acc[i], 0, 0, 0);
#pragma unroll
    for (int i = 0; i < 4; ++i)
      acc[i] = __builtin_amdgcn_mfma_f32_16x16x32_bf16(a[i][2], hf1, acc[i], 0, 0, 0);

    // activations + state update; lane-local (regs 0..3 = i,f,g,o of one unit)
    float hv[4];
#pragma unroll
    for (int i = 0; i < 4; ++i) {
      float4v g4 = acc[i];
      float iv = sigf(g4[0]);
      float fv = sigf(g4[1]);
      float gv = tanh_f(g4[2]);
      float ov = sigf(g4[3]);
      float cn = fv * c_state[i] + iv * gv;
      c_state[i] = cn;
      hv[i] = ov * tanh_f(cn);
    }
    // packed bf16 convert, then 4 b16 stores (units 16w+4i+q, row l15)
    unsigned p01 = pk2(hv[0], hv[1]);
    unsigned p23 = pk2(hv[2], hv[3]);
    hs[nxt][l15][16 * w + 0 + q]  = (short)(p01 & 0xFFFF);
    hs[nxt][l15][16 * w + 4 + q]  = (short)(p01 >> 16);
    hs[nxt][l15][16 * w + 8 + q]  = (short)(p23 & 0xFFFF);
    hs[nxt][l15][16 * w + 12 + q] = (short)(p23 >> 16);

    __syncthreads();
  }

  // ---- FC epilogue: final h in hs[0] (t=27 wrote nxt = 0) ------------------
  if (tid < ROWS * OUT_DIM) {           // 160 outputs, o-major -> coalesced
    const int r = tid / OUT_DIM;
    const int o = tid - r * OUT_DIM;
    float s = b_fc[o];
#pragma unroll
    for (int j = 0; j < HID; ++j)
      s += bf2f(hs[0][r][j]) * W_fc[o * HID + j];
    out[(b0 + r) * OUT_DIM + o] = s;
  }
}

extern "C" void kernel_launch(void* const* d_in, const int* in_sizes, int n_in,
                              void* d_out, int out_size, void* d_ws, size_t ws_size,
                              hipStream_t stream) {
  const float* x    = (const float*)d_in[0];
  const float* W_ih = (const float*)d_in[1];
  const float* W_hh = (const float*)d_in[2];
  const float* b_ih = (const float*)d_in[3];
  const float* b_hh = (const float*)d_in[4];
  const float* W_fc = (const float*)d_in[5];
  const float* b_fc = (const float*)d_in[6];
  float* out = (float*)d_out;

  dim3 grid(B_TOT / ROWS);   // 1024 blocks -> 4 blocks/CU co-resident
  dim3 block(THREADS);
  lstm_mfma2<<<grid, block, 0, stream>>>(x, W_ih, W_hh, b_ih, b_hh, W_fc, b_fc, out);
}

// Round 4
// 158.266 us; speedup vs baseline: 1.0159x; 1.0159x over previous
//
#include <hip/hip_runtime.h>
#include <hip/hip_bf16.h>

// LSTM_71382356459716 R3: R2 structure + pinned occupancy (the R2 regression
// was the register allocator targeting 8 waves/SIMD @ 64 VGPRs and spilling
// the 48-VGPR stationary weight set to scratch: WRITE_SIZE 640KB -> 22MB).
// amdgpu_waves_per_eu(4,4) plans for exactly 4 waves/SIMD (4 blocks/CU),
// giving the full 128-VGPR budget -> no spills.
// Structure: 1024 blocks x 4 waves; wave owns 16 hidden units (4 M-tiles of
// the unit-major-permuted 256x96 gate matrix, stationary in registers); block
// owns 16 batch rows. x B-frags straight from global, bias rides as MFMA C,
// packed bf16 converts. LDS: double-buffered h (2x16x72 bf16 = 4.6 KB),
// row stride 144B (odd multiple of 16B -> conflict-free ds_read_b128).

namespace {
constexpr int B_TOT   = 16384;
constexpr int T_STEPS = 28;
constexpr int IN_DIM  = 28;
constexpr int HID     = 64;
constexpr int OUT_DIM = 10;
constexpr int ROWS    = 16;    // batch rows per block -> 1024 blocks, 4/CU
constexpr int THREADS = 256;   // 4 waves
constexpr int KP      = 72;    // h row stride in shorts (144 B)
constexpr int XROW    = T_STEPS * IN_DIM;  // 784 floats per batch row
}

typedef __attribute__((ext_vector_type(8))) short short8v;   // 8 bf16
typedef __attribute__((ext_vector_type(4))) float float4v;
typedef __attribute__((ext_vector_type(4))) int   int4v;

__device__ __forceinline__ short f2bf_cold(float f) {   // init path only
  union { float f; unsigned u; } v; v.f = f;
  unsigned r = v.u + 0x7FFFu + ((v.u >> 16) & 1u);
  return (short)(r >> 16);
}
__device__ __forceinline__ float bf2f(short s) {
  union { unsigned u; float f; } v; v.u = ((unsigned)(unsigned short)s) << 16;
  return v.f;
}
__device__ __forceinline__ unsigned pk2(float a, float b) {  // 2xf32 -> packed bf16x2
  __hip_bfloat162 h = __float22bfloat162_rn(float2{a, b});
  union { __hip_bfloat162 h; unsigned u; } cv; cv.h = h; return cv.u;
}
__device__ __forceinline__ float sigf(float v) {
  return __builtin_amdgcn_rcpf(1.0f + __expf(-v));
}
__device__ __forceinline__ float tanh_f(float v) {
  return 2.0f * __builtin_amdgcn_rcpf(1.0f + __expf(-2.0f * v)) - 1.0f;
}

__global__ __attribute__((amdgpu_flat_work_group_size(THREADS, THREADS),
                          amdgpu_waves_per_eu(4, 4)))
void lstm_mfma3(const float* __restrict__ x, const float* __restrict__ W_ih,
                const float* __restrict__ W_hh, const float* __restrict__ b_ih,
                const float* __restrict__ b_hh, const float* __restrict__ W_fc,
                const float* __restrict__ b_fc, float* __restrict__ out) {
  __shared__ short hs[2][ROWS][KP];   // [buf][row][unit], bf16

  const int tid  = threadIdx.x;
  const int lane = tid & 63;
  const int w    = tid >> 6;      // wave 0..3 -> units 16w..16w+15
  const int l15  = lane & 15;
  const int q    = lane >> 4;     // 0..3
  const int b0   = blockIdx.x * ROWS;

  // ---- stationary A (weights), gate rows permuted unit-major m = unit*4+type
  // A-frag: lane holds A[m = 16*mt + l15][k = kc*32 + q*8 + j].
  // k: 0..27 = W_ih cols, 28..31 = 0, 32..95 = W_hh cols.
  short8v a[4][3];
  float4v bias[4];
#pragma unroll
  for (int i = 0; i < 4; ++i) {
    const int mt   = 4 * w + i;
    const int m    = 16 * mt + l15;
    const int unit = m >> 2, type = m & 3;
    const int g    = type * 64 + unit;
#pragma unroll
    for (int kc = 0; kc < 3; ++kc) {
      short8v frag;
#pragma unroll
      for (int j = 0; j < 8; ++j) {
        const int k = kc * 32 + q * 8 + j;
        float v = 0.0f;
        if (k < IN_DIM)   v = W_ih[g * IN_DIM + k];
        else if (k >= 32) v = W_hh[g * HID + (k - 32)];
        frag[j] = f2bf_cold(v);
      }
      a[i][kc] = frag;
    }
    const int ub = 4 * mt + q;    // the unit this lane's C regs belong to
    float4v bv;
#pragma unroll
    for (int r = 0; r < 4; ++r) bv[r] = b_ih[r * 64 + ub] + b_hh[r * 64 + ub];
    bias[i] = bv;
  }

  // zero h buffers
  for (int idx = tid; idx < 2 * ROWS * KP; idx += THREADS) (&hs[0][0][0])[idx] = 0;
  __syncthreads();

  // ---- x direct-from-global: lane (l15,q) covers row b0+l15, k = q*8..q*8+7
  const float* xrow = x + (size_t)(b0 + l15) * XROW + q * 8;
  float4 lo = *(const float4*)xrow;                       // t = 0
  float4 hi = {0.f, 0.f, 0.f, 0.f};
  if (q < 3) hi = *(const float4*)(xrow + 4);             // q==3: k 28..31 are pad

  float c_state[4] = {0.f, 0.f, 0.f, 0.f};

  for (int t = 0; t < T_STEPS; ++t) {
    const int cur = t & 1, nxt = cur ^ 1;

    // pack this step's x frag (consumes lo/hi loaded last iteration)
    int4v xi;
    xi[0] = pk2(lo.x, lo.y); xi[1] = pk2(lo.z, lo.w);
    xi[2] = pk2(hi.x, hi.y); xi[3] = pk2(hi.z, hi.w);
    union { int4v i; short8v s; } xb; xb.i = xi;

    // h B-frags from LDS: lane holds B[k = 32 + kc*32 + q*8 + j][n = l15]
    short8v hf0 = *(const short8v*)&hs[cur][l15][q * 8];
    short8v hf1 = *(const short8v*)&hs[cur][l15][32 + q * 8];

    // prefetch next step's x (latency hides under MFMA + activations)
    if (t + 1 < T_STEPS) {
      const float* xp = xrow + (t + 1) * IN_DIM;
      lo = *(const float4*)xp;
      if (q < 3) hi = *(const float4*)(xp + 4);
    }

    float4v acc[4];
#pragma unroll
    for (int i = 0; i < 4; ++i)
      acc[i] = __builtin_amdgcn_mfma_f32_16x16x32_bf16(a[i][0], xb.s, bias[i], 0, 0, 0);
#pragma unroll
    for (int i = 0; i < 4; ++i)
      acc[i] = __builtin_amdgcn_mfma_f32_16x16x32_bf16(a[i][1], hf0, acc[i], 0, 0, 0);
#pragma unroll
    for (int i = 0; i < 4; ++i)
      acc[i] = __builtin_amdgcn_mfma_f32_16x16x32_bf16(a[i][2], hf1, acc[i], 0, 0, 0);

    // activations + state update; lane-local (regs 0..3 = i,f,g,o of one unit)
    float hv[4];
#pragma unroll
    for (int i = 0; i < 4; ++i) {
      float4v g4 = acc[i];
      float iv = sigf(g4[0]);
      float fv = sigf(g4[1]);
      float gv = tanh_f(g4[2]);
      float ov = sigf(g4[3]);
      float cn = fv * c_state[i] + iv * gv;
      c_state[i] = cn;
      hv[i] = ov * tanh_f(cn);
    }
    // packed bf16 convert, then 4 b16 stores (units 16w+4i+q, row l15)
    unsigned p01 = pk2(hv[0], hv[1]);
    unsigned p23 = pk2(hv[2], hv[3]);
    hs[nxt][l15][16 * w + 0 + q]  = (short)(p01 & 0xFFFF);
    hs[nxt][l15][16 * w + 4 + q]  = (short)(p01 >> 16);
    hs[nxt][l15][16 * w + 8 + q]  = (short)(p23 & 0xFFFF);
    hs[nxt][l15][16 * w + 12 + q] = (short)(p23 >> 16);

    __syncthreads();
  }

  // ---- FC epilogue: final h in hs[0] (t=27 wrote nxt = 0) ------------------
  if (tid < ROWS * OUT_DIM) {           // 160 outputs, o-major -> coalesced
    const int r = tid / OUT_DIM;
    const int o = tid - r * OUT_DIM;
    float s = b_fc[o];
#pragma unroll
    for (int j = 0; j < HID; ++j)
      s += bf2f(hs[0][r][j]) * W_fc[o * HID + j];
    out[(b0 + r) * OUT_DIM + o] = s;
  }
}

extern "C" void kernel_launch(void* const* d_in, const int* in_sizes, int n_in,
                              void* d_out, int out_size, void* d_ws, size_t ws_size,
                              hipStream_t stream) {
  const float* x    = (const float*)d_in[0];
  const float* W_ih = (const float*)d_in[1];
  const float* W_hh = (const float*)d_in[2];
  const float* b_ih = (const float*)d_in[3];
  const float* b_hh = (const float*)d_in[4];
  const float* W_fc = (const float*)d_in[5];
  const float* b_fc = (const float*)d_in[6];
  float* out = (float*)d_out;

  dim3 grid(B_TOT / ROWS);   // 1024 blocks -> 4 blocks/CU co-resident
  dim3 block(THREADS);
  lstm_mfma3<<<grid, block, 0, stream>>>(x, W_ih, W_hh, b_ih, b_hh, W_fc, b_fc, out);
}

// Round 5
// 145.579 us; speedup vs baseline: 1.1044x; 1.0871x over previous
//
#include <hip/hip_runtime.h>
#include <hip/hip_bf16.h>

// LSTM_71382356459716 R4: R2/R3 structure, minus the register spill.
// R2/R3 spilled ~21 dwords/thread (WRITE_SIZE 640KB -> 22MB): live set
// (A 48 + bias 16 + acc 16 + x 8 + frags 12 + misc) exceeded the 128-reg
// unified budget at 4 waves/EU. Fix: fold bias into the weights -- x's
// k=28 pad slot is forced to 1.0 and W column 28 carries (b_ih+b_hh), so
// bias enters via the existing k-chunk-0 MFMA and the 16 bias VGPRs (and
// the acc-init) disappear. Demand ~103 < 128.
// Structure: 1024 blocks x 4 waves; wave owns 16 hidden units (4 M-tiles of
// the unit-major-permuted 256x96 gate matrix, stationary in registers); block
// owns 16 batch rows. x B-frags straight from global, packed bf16 converts.
// LDS: double-buffered h (2x16x72 bf16 = 4.6 KB), row stride 144 B.

namespace {
constexpr int B_TOT   = 16384;
constexpr int T_STEPS = 28;
constexpr int IN_DIM  = 28;
constexpr int HID     = 64;
constexpr int OUT_DIM = 10;
constexpr int ROWS    = 16;    // batch rows per block -> 1024 blocks, 4/CU
constexpr int THREADS = 256;   // 4 waves
constexpr int KP      = 72;    // h row stride in shorts (144 B)
constexpr int XROW    = T_STEPS * IN_DIM;  // 784 floats per batch row
}

typedef __attribute__((ext_vector_type(8))) short short8v;   // 8 bf16
typedef __attribute__((ext_vector_type(4))) float float4v;
typedef __attribute__((ext_vector_type(4))) int   int4v;

__device__ __forceinline__ short f2bf_cold(float f) {   // init path only
  union { float f; unsigned u; } v; v.f = f;
  unsigned r = v.u + 0x7FFFu + ((v.u >> 16) & 1u);
  return (short)(r >> 16);
}
__device__ __forceinline__ float bf2f(short s) {
  union { unsigned u; float f; } v; v.u = ((unsigned)(unsigned short)s) << 16;
  return v.f;
}
__device__ __forceinline__ unsigned pk2(float a, float b) {  // 2xf32 -> packed bf16x2
  __hip_bfloat162 h = __float22bfloat162_rn(float2{a, b});
  union { __hip_bfloat162 h; unsigned u; } cv; cv.h = h; return cv.u;
}
__device__ __forceinline__ float sigf(float v) {
  return __builtin_amdgcn_rcpf(1.0f + __expf(-v));
}
__device__ __forceinline__ float tanh_f(float v) {
  return 2.0f * __builtin_amdgcn_rcpf(1.0f + __expf(-2.0f * v)) - 1.0f;
}

__global__ __attribute__((amdgpu_flat_work_group_size(THREADS, THREADS),
                          amdgpu_waves_per_eu(4, 4)))
void lstm_mfma4(const float* __restrict__ x, const float* __restrict__ W_ih,
                const float* __restrict__ W_hh, const float* __restrict__ b_ih,
                const float* __restrict__ b_hh, const float* __restrict__ W_fc,
                const float* __restrict__ b_fc, float* __restrict__ out) {
  __shared__ short hs[2][ROWS][KP];   // [buf][row][unit], bf16

  const int tid  = threadIdx.x;
  const int lane = tid & 63;
  const int w    = tid >> 6;      // wave 0..3 -> units 16w..16w+15
  const int l15  = lane & 15;
  const int q    = lane >> 4;     // 0..3
  const int b0   = blockIdx.x * ROWS;

  // ---- stationary A (weights+bias), gate rows permuted unit-major ----------
  // A-frag: lane holds A[m = 16*mt + l15][k = kc*32 + q*8 + j].
  // k: 0..27 = W_ih cols, 28 = bias column (x[28] == 1), 29..31 = 0,
  // 32..95 = W_hh cols.
  short8v a[4][3];
#pragma unroll
  for (int i = 0; i < 4; ++i) {
    const int mt   = 4 * w + i;
    const int m    = 16 * mt + l15;
    const int unit = m >> 2, type = m & 3;
    const int g    = type * 64 + unit;
#pragma unroll
    for (int kc = 0; kc < 3; ++kc) {
      short8v frag;
#pragma unroll
      for (int j = 0; j < 8; ++j) {
        const int k = kc * 32 + q * 8 + j;
        float v = 0.0f;
        if (k < IN_DIM)        v = W_ih[g * IN_DIM + k];
        else if (k == IN_DIM)  v = b_ih[g] + b_hh[g];     // bias column
        else if (k >= 32)      v = W_hh[g * HID + (k - 32)];
        frag[j] = f2bf_cold(v);
      }
      a[i][kc] = frag;
    }
  }

  // zero h buffers
  for (int idx = tid; idx < 2 * ROWS * KP; idx += THREADS) (&hs[0][0][0])[idx] = 0;
  __syncthreads();

  // ---- x direct-from-global: lane (l15,q) covers row b0+l15, k = q*8..q*8+7
  const float* xrow = x + (size_t)(b0 + l15) * XROW + q * 8;
  float4 lo = *(const float4*)xrow;                       // t = 0
  float4 hi = {0.f, 0.f, 0.f, 0.f};
  if (q < 3) hi = *(const float4*)(xrow + 4);
  else       hi.x = 1.0f;          // k==28 constant-1 feeds the bias column

  float c_state[4] = {0.f, 0.f, 0.f, 0.f};

  for (int t = 0; t < T_STEPS; ++t) {
    const int cur = t & 1, nxt = cur ^ 1;

    // pack this step's x frag (consumes lo/hi loaded last iteration)
    int4v xi;
    xi[0] = pk2(lo.x, lo.y); xi[1] = pk2(lo.z, lo.w);
    xi[2] = pk2(hi.x, hi.y); xi[3] = pk2(hi.z, hi.w);
    union { int4v i; short8v s; } xb; xb.i = xi;

    // h B-frags from LDS: lane holds B[k = 32 + kc*32 + q*8 + j][n = l15]
    short8v hf0 = *(const short8v*)&hs[cur][l15][q * 8];
    short8v hf1 = *(const short8v*)&hs[cur][l15][32 + q * 8];

    // prefetch next step's x (latency hides under MFMA + activations);
    // q==3 keeps hi = (1,0,0,0) forever.
    if (t + 1 < T_STEPS) {
      const float* xp = xrow + (t + 1) * IN_DIM;
      lo = *(const float4*)xp;
      if (q < 3) hi = *(const float4*)(xp + 4);
    }

    const float4v zero4 = {0.f, 0.f, 0.f, 0.f};
    float4v acc[4];
#pragma unroll
    for (int i = 0; i < 4; ++i)
      acc[i] = __builtin_amdgcn_mfma_f32_16x16x32_bf16(a[i][0], xb.s, zero4, 0, 0, 0);
#pragma unroll
    for (int i = 0; i < 4; ++i)
      acc[i] = __builtin_amdgcn_mfma_f32_16x16x32_bf16(a[i][1], hf0, acc[i], 0, 0, 0);
#pragma unroll
    for (int i = 0; i < 4; ++i)
      acc[i] = __builtin_amdgcn_mfma_f32_16x16x32_bf16(a[i][2], hf1, acc[i], 0, 0, 0);

    // activations + state update; lane-local (regs 0..3 = i,f,g,o of one unit)
    float hv[4];
#pragma unroll
    for (int i = 0; i < 4; ++i) {
      float4v g4 = acc[i];
      float iv = sigf(g4[0]);
      float fv = sigf(g4[1]);
      float gv = tanh_f(g4[2]);
      float ov = sigf(g4[3]);
      float cn = fv * c_state[i] + iv * gv;
      c_state[i] = cn;
      hv[i] = ov * tanh_f(cn);
    }
    // packed bf16 convert, then 4 b16 stores (units 16w+4i+q, row l15)
    unsigned p01 = pk2(hv[0], hv[1]);
    unsigned p23 = pk2(hv[2], hv[3]);
    hs[nxt][l15][16 * w + 0 + q]  = (short)(p01 & 0xFFFF);
    hs[nxt][l15][16 * w + 4 + q]  = (short)(p01 >> 16);
    hs[nxt][l15][16 * w + 8 + q]  = (short)(p23 & 0xFFFF);
    hs[nxt][l15][16 * w + 12 + q] = (short)(p23 >> 16);

    __syncthreads();
  }

  // ---- FC epilogue: final h in hs[0] (t=27 wrote nxt = 0) ------------------
  if (tid < ROWS * OUT_DIM) {           // 160 outputs, o-major -> coalesced
    const int r = tid / OUT_DIM;
    const int o = tid - r * OUT_DIM;
    float s = b_fc[o];
#pragma unroll
    for (int j = 0; j < HID; ++j)
      s += bf2f(hs[0][r][j]) * W_fc[o * HID + j];
    out[(b0 + r) * OUT_DIM + o] = s;
  }
}

extern "C" void kernel_launch(void* const* d_in, const int* in_sizes, int n_in,
                              void* d_out, int out_size, void* d_ws, size_t ws_size,
                              hipStream_t stream) {
  const float* x    = (const float*)d_in[0];
  const float* W_ih = (const float*)d_in[1];
  const float* W_hh = (const float*)d_in[2];
  const float* b_ih = (const float*)d_in[3];
  const float* b_hh = (const float*)d_in[4];
  const float* W_fc = (const float*)d_in[5];
  const float* b_fc = (const float*)d_in[6];
  float* out = (float*)d_out;

  dim3 grid(B_TOT / ROWS);   // 1024 blocks -> 4 blocks/CU co-resident
  dim3 block(THREADS);
  lstm_mfma4<<<grid, block, 0, stream>>>(x, W_ih, W_hh, b_ih, b_hh, W_fc, b_fc, out);
}